// Round 13
// baseline (135.936 us; speedup 1.0000x reference)
//
#include <hip/hip_runtime.h>
#include <hip/hip_fp16.h>

#define TWO_PI_F 6.283185307179586f

__device__ __forceinline__ float clamp02pi(float x) {
    return fminf(fmaxf(x, 0.0f), TWO_PI_F);
}

__device__ __forceinline__ float2 cmul(const float2 a, const float2 b) {
    return make_float2(a.x * b.x - a.y * b.y, a.x * b.y + a.y * b.x);
}
__device__ __forceinline__ float2 cadd(const float2 a, const float2 b) {
    return make_float2(a.x + b.x, a.y + b.y);
}
__device__ __forceinline__ float2 cscale(const float s, const float2 a) {
    return make_float2(s * a.x, s * a.y);
}
__device__ __forceinline__ float2 imul(const float r, const float2 e) {  // i*r*e
    return make_float2(-r * e.y, r * e.x);
}
__device__ __forceinline__ float2 cfma(const float2 acc, const float2 a, const float2 b) {
    return make_float2(acc.x + a.x * b.x - a.y * b.y,
                       acc.y + a.x * b.y + a.y * b.x);
}

// half2 <-> float2 via bit_cast (register-only).
__device__ __forceinline__ float2 h2f(const unsigned u) {
    return __half22float2(__builtin_bit_cast(__half2, u));
}
__device__ __forceinline__ unsigned f2h(const float2 f) {
    return __builtin_bit_cast(unsigned, __float22half2_rn(f));
}

// Band-4 composition of row r for one 4-layer step, WINDOWED pair coefs
// (math verbatim R12-R18 — verified, absmax 7.45e-9 on the fp16 path).
__device__ __forceinline__ void compose_row_w(
    const float4 (*sE)[72], const float4 (*sO)[72], const int r, const int P0,
    float4& h0, float4& h1)
{
    float2 f0, f1, f2, f3;
    if (r == 0) {
        const float4 q1 = sE[1][0], q0 = sE[0][0];   // P0 == 0 for quarter 0
        const float2 e1 = make_float2(q1.x, q1.y);
        const float2 e0 = make_float2(q0.x, q0.y);
        const float2 v2 = cscale(q1.z, e1);
        const float2 v3 = make_float2(0.0f, q1.w);
        f2 = cadd(cmul(v2, cscale(q0.z, e0)), cmul(v3, imul(q0.w, e0)));
        f3 = cadd(cmul(v2, make_float2(0.0f, q0.w)), cscale(q0.z, v3));
        f0 = make_float2(0.0f, 0.0f);
        f1 = make_float2(0.0f, 0.0f);
    } else {
        const int pidx = ((r - 1) >> 1) - P0;
        const int qidx = min(((r - 1) >> 1) + 1, 255) - P0;
        const float4 qO1 = sO[1][pidx], qO0 = sO[0][pidx];
        const float2 eO1 = make_float2(qO1.x, qO1.y);
        const float2 eO0 = make_float2(qO0.x, qO0.y);
        float2 w1, w2;
        if (r & 1) { w1 = cscale(qO1.z, eO1); w2 = make_float2(0.0f, qO1.w); }
        else       { w1 = imul(qO1.w, eO1);   w2 = make_float2(qO1.z, 0.0f); }
        const float2 u1 = cadd(cmul(w1, cscale(qO0.z, eO0)),
                               cmul(w2, imul(qO0.w, eO0)));
        const float2 u2 = cadd(cmul(w1, make_float2(0.0f, qO0.w)),
                               cscale(qO0.z, w2));
        const float4 qE1p = sE[1][pidx], qE1q = sE[1][qidx];
        const float4 qE0p = sE[0][pidx], qE0q = sE[0][qidx];
        const float2 eE1p = make_float2(qE1p.x, qE1p.y);
        const float2 eE1q = make_float2(qE1q.x, qE1q.y);
        const float2 eE0p = make_float2(qE0p.x, qE0p.y);
        const float2 eE0q = make_float2(qE0q.x, qE0q.y);
        const float2 v0 = cmul(u1, imul(qE1p.w, eE1p));
        const float2 v1 = cscale(qE1p.z, u1);
        const float2 v2 = cmul(u2, cscale(qE1q.z, eE1q));
        const float2 v3 = cmul(u2, make_float2(0.0f, qE1q.w));
        f0 = cadd(cmul(v0, cscale(qE0p.z, eE0p)), cmul(v1, imul(qE0p.w, eE0p)));
        f1 = cadd(cmul(v0, make_float2(0.0f, qE0p.w)), cscale(qE0p.z, v1));
        f2 = cadd(cmul(v2, cscale(qE0q.z, eE0q)), cmul(v3, imul(qE0q.w, eE0q)));
        f3 = cadd(cmul(v2, make_float2(0.0f, qE0q.w)), cscale(qE0q.z, v3));
    }
    h0 = make_float4(f0.x, f0.y, f1.x, f1.y);
    h1 = make_float4(f2.x, f2.y, f3.x, f3.y);
}

// ---------------------------------------------------------------------------
// Kernel 1: quarter-superstep composition — R8 rebalanced version (verified).
// Row-direct output layout:
//   Mch8[j*1024 + r] = band cols 0..3 ; Mch8[j*1024 + 512 + r] = cols 4..7
// ---------------------------------------------------------------------------
__global__ __launch_bounds__(320) void compose8q_kernel(
    const float* __restrict__ pe, const float* __restrict__ po,
    const float* __restrict__ le, const float* __restrict__ ie,
    const float* __restrict__ lo, const float* __restrict__ io,
    uint4* __restrict__ Mch8)
{
    const int q = blockIdx.x;
    const int j = q >> 2;
    const int quarter = q & 3;
    const int R0 = 128 * quarter;
    const int P0 = (quarter == 0) ? 0 : ((R0 - 3) >> 1);
    const int t = threadIdx.x;

    __shared__ float4 sE[4][72];
    __shared__ float4 sO[4][72];
    __shared__ float4 B4[2][134][2];

    // ---- Phase A: stage pair-coef window [P0, P0+72) (2 passes @320) ----
    for (int it = t; it < 576; it += 320) {
        const int half = it / 288;
        const int rem  = it % 288;
        const int sub  = rem / 72;
        const int w    = rem % 72;
        const int p    = P0 + w;
        if (p > 255) continue;
        if (half == 0) {
            const int idx = (4 * j + sub) * 256 + p;
            float s, c;
            __sincosf(clamp02pi(pe[idx]), &s, &c);
            const float a = sqrtf(1.0f - le[idx]);
            sE[sub][w] = make_float4(c, s, a * sqrtf(0.5f + ie[idx]),
                                           a * sqrtf(0.5f - ie[idx]));
        } else {
            float4 qv = make_float4(1.0f, 0.0f, 1.0f, 0.0f);
            if (p < 255) {
                const int odx = (4 * j + sub) * 255 + p;
                float s, c;
                __sincosf(clamp02pi(po[odx]), &s, &c);
                const float a = sqrtf(1.0f - lo[odx]);
                qv = make_float4(c, s, a * sqrtf(0.5f + io[odx]),
                                       a * sqrtf(0.5f - io[odx]));
            }
            sO[sub][w] = qv;
        }
    }
    __syncthreads();

    // ---- Phase B: band-4 for both child steps, rows [R0-2, R0+131] ----
    if (t < 268) {
        const int s = t / 134, slot = t % 134;
        const int row = R0 - 2 + slot;
        if (row >= 0 && row <= 511) {
            float4 h0, h1;
            compose_row_w(&sE[2 * s], &sO[2 * s], row, P0, h0, h1);
            B4[s][slot][0] = h0;
            B4[s][slot][1] = h1;
        }
    }
    __syncthreads();

    // ---- Phase C: band-8 product, rows R0..R0+127, 2 threads/row ----
    if (t < 256) {
        const int rr_  = t & 127;
        const int half = t >> 7;
        const int r = R0 + rr_;
        const int base = (r & 1) ? (r - 1) : (r - 2);
        const int sr = rr_ + 2;
        const float4 wv0 = B4[1][sr][0], wv1 = B4[1][sr][1];
        const float2 w0 = make_float2(wv0.x, wv0.y), w1 = make_float2(wv0.z, wv0.w);
        const float2 w2 = make_float2(wv1.x, wv1.y), w3 = make_float2(wv1.z, wv1.w);
        uint4* dst = Mch8 + (size_t)j * 1024 + r;     // row-direct layout

        if (half == 0) {
            float2 p0 = make_float2(0.f,0.f), p1 = p0, p2 = p0, p3 = p0;
            {   const int k = min(max(base, 0), 511) - (R0 - 2);
                const float4 a = B4[0][k][0], b = B4[0][k][1];
                p0 = cfma(p0, w0, make_float2(a.x, a.y));
                p1 = cfma(p1, w0, make_float2(a.z, a.w));
                p2 = cfma(p2, w0, make_float2(b.x, b.y));
                p3 = cfma(p3, w0, make_float2(b.z, b.w)); }
            {   const int k = min(max(base + 1, 0), 511) - (R0 - 2);
                const float4 a = B4[0][k][0];
                p2 = cfma(p2, w1, make_float2(a.x, a.y));
                p3 = cfma(p3, w1, make_float2(a.z, a.w)); }
            {   const int k = min(max(base + 2, 0), 511) - (R0 - 2);
                const float4 a = B4[0][k][0];
                p2 = cfma(p2, w2, make_float2(a.x, a.y));
                p3 = cfma(p3, w2, make_float2(a.z, a.w)); }
            dst[0] = make_uint4(f2h(p0), f2h(p1), f2h(p2), f2h(p3));
        } else {
            float2 p4 = make_float2(0.f,0.f), p5 = p4, p6 = p4, p7 = p4;
            {   const int k = min(max(base + 1, 0), 511) - (R0 - 2);
                const float4 b = B4[0][k][1];
                p4 = cfma(p4, w1, make_float2(b.x, b.y));
                p5 = cfma(p5, w1, make_float2(b.z, b.w)); }
            {   const int k = min(max(base + 2, 0), 511) - (R0 - 2);
                const float4 b = B4[0][k][1];
                p4 = cfma(p4, w2, make_float2(b.x, b.y));
                p5 = cfma(p5, w2, make_float2(b.z, b.w)); }
            {   const int k = min(max(base + 3, 0), 511) - (R0 - 2);
                const float4 a = B4[0][k][0], b = B4[0][k][1];
                p4 = cfma(p4, w3, make_float2(a.x, a.y));
                p5 = cfma(p5, w3, make_float2(a.z, a.w));
                p6 = cfma(p6, w3, make_float2(b.x, b.y));
                p7 = cfma(p7, w3, make_float2(b.z, b.w)); }
            dst[512] = make_uint4(f2h(p4), f2h(p5), f2h(p6), f2h(p7));
        }
    }
}

// Complex FMA with fp16-packed coefficient, f32 accumulate, via v_fma_mix
// (exact f16->f32 convert folded into the f32 fma; R4/R5 measured
// bit-identical absmax vs the h2f-then-cfma path).
__device__ __forceinline__ float2 chmix(float2 acc, const unsigned h,
                                        const float2 b)
{
    const __half2 k = __builtin_bit_cast(__half2, h);
    const float kx = __low2float(k);
    const float ky = __high2float(k);
    acc.x = fmaf(kx,  b.x, acc.x);
    acc.x = fmaf(-ky, b.y, acc.x);
    acc.y = fmaf(kx,  b.y, acc.y);
    acc.y = fmaf(ky,  b.x, acc.y);
    return acc;
}

// Band-8 row apply: coefs ca (slots w0,w1) then cb (slots w2,w3), ascending —
// exact order of the verified path (R4/R5-verified numerics).
__device__ __forceinline__ float2 row8m(const uint4 ca, const uint4 cb,
    const float4 w0, const float4 w1, const float4 w2, const float4 w3)
{
    float2 a = make_float2(0.f, 0.f);
    a = chmix(a, ca.x, make_float2(w0.x, w0.y));
    a = chmix(a, ca.y, make_float2(w0.z, w0.w));
    a = chmix(a, ca.z, make_float2(w1.x, w1.y));
    a = chmix(a, ca.w, make_float2(w1.z, w1.w));
    a = chmix(a, cb.x, make_float2(w2.x, w2.y));
    a = chmix(a, cb.y, make_float2(w2.z, w2.w));
    a = chmix(a, cb.z, make_float2(w3.x, w3.y));
    a = chmix(a, cb.w, make_float2(w3.z, w3.w));
    return a;
}

// One mesh superstep body: read window from SR (q2 from registers), prefetch
// next coefs into cn[4], apply coefs cc[4] under narrow setprio, write state
// to SW, counted barrier. All addressing static (SR/SW are named arrays).
// Math bitwise-identical to the R12-verified path.
#define MESH_STEP(SR, SW, cc, cn, NB)                                         \
    {                                                                         \
        const float4 q0 = SR[t],     q1 = SR[t + 1],                          \
                     q3 = SR[t + 3], q4 = SR[t + 4];                          \
        const float4 q2 = make_float4(Y0.x, Y0.y, Y1.x, Y1.y);                \
        const int nb = (NB);                                                  \
        cn[0] = Mch[nb + r0]; cn[1] = Mch[nb + 512 + r0];                     \
        cn[2] = Mch[nb + r1]; cn[3] = Mch[nb + 512 + r1];                     \
        __builtin_amdgcn_s_setprio(1);                                        \
        Y0 = row8m(cc[0], cc[1], q0, q1, q2, q3);                             \
        Y1 = row8m(cc[2], cc[3], q1, q2, q3, q4);                             \
        __builtin_amdgcn_s_setprio(0);                                        \
        SW[t + 2] = make_float4(Y0.x, Y0.y, Y1.x, Y1.y);                      \
        __builtin_amdgcn_sched_barrier(0);                                    \
        asm volatile("s_waitcnt lgkmcnt(0)" ::: "memory");                    \
        __builtin_amdgcn_s_barrier();                                         \
        __builtin_amdgcn_sched_barrier(0);                                    \
    }

// ---------------------------------------------------------------------------
// Kernel 2: PAIR-per-thread band-8 scan — R12 config (best measured: 62.1 us;
// counted barrier + narrow setprio + q2-from-registers + reads-first) with
// R13's register-rotation elimination: hand-unrolled x2 with NAMED coef sets
// cA/cB and NAMED buffers S0/S1 (sub-step A: read S0, coefs cA, prefetch cB,
// write S1; sub-step B: roles swapped). Removes the 32 v_mov_b32/thread/iter
// the unroll-1 loop needed to rotate n* into c* (~11% of the now-binding
// VALU budget) and makes all LDS addressing static. Math bitwise-identical;
// absmax must stay exactly 7.450581e-9.
// ---------------------------------------------------------------------------
__global__ __launch_bounds__(256) void mesh8p_kernel(
    const uint4* __restrict__ Mch,
    const float* __restrict__ pout,
    float* __restrict__ out, const int out_size)
{
    const int t   = threadIdx.x;   // pair 0..255
    const int col = blockIdx.x;    // column 0..511
    const int r0  = 2 * t, r1 = r0 + 1;

    __shared__ float4 S0[264];     // [pair+2] = {T.x,T.y,B.x,B.y}
    __shared__ float4 S1[264];

    float2 Y0 = make_float2((r0 == col) ? 1.0f : 0.0f, 0.0f);
    float2 Y1 = make_float2((r1 == col) ? 1.0f : 0.0f, 0.0f);
    S0[t + 2] = make_float4(Y0.x, Y0.y, Y1.x, Y1.y);
    if (t < 2) {
        const float4 z = make_float4(0.f, 0.f, 0.f, 0.f);
        S0[t] = z; S1[t] = z;
        S0[258 + t] = z; S1[258 + t] = z;
    }

    uint4 cA[4], cB[4];            // {c0e, c1e, c0o, c1o}
    cA[0] = Mch[r0]; cA[1] = Mch[512 + r0];
    cA[2] = Mch[r1]; cA[3] = Mch[512 + r1];
    __syncthreads();

#pragma unroll 1
    for (int i = 0; i < 64; ++i) {
        // superstep 2i:   S0 -> S1, coefs cA, prefetch -> cB
        MESH_STEP(S0, S1, cA, cB, (2 * i + 1) * 1024)
        // superstep 2i+1: S1 -> S0, coefs cB, prefetch -> cA (wrap at end ok)
        MESH_STEP(S1, S0, cB, cA, ((2 * i + 2) & 127) * 1024)
    }

    // ---- output phase; expected output = Re(M), row-major, guarded ----
    float s0, cc0, s1, cc1;
    __sincosf(clamp02pi(pout[r0]), &s0, &cc0);
    __sincosf(clamp02pi(pout[r1]), &s1, &cc1);
    const int o0 = r0 * 512 + col;
    const int o1 = r1 * 512 + col;
    if (o0 < out_size) out[o0] = cc0 * Y0.x - s0 * Y0.y;
    if (o1 < out_size) out[o1] = cc1 * Y1.x - s1 * Y1.y;
}

// ---------------------------------------------------------------------------
// Fallback (verbatim R5 kernel, known-passing) — used only if ws too small.
// ---------------------------------------------------------------------------
__global__ __launch_bounds__(256) void mesh_kernel(
    const float* __restrict__ pe, const float* __restrict__ po,
    const float* __restrict__ pout,
    const float* __restrict__ le, const float* __restrict__ ie,
    const float* __restrict__ lo, const float* __restrict__ io,
    float* __restrict__ out, const int out_size)
{
    const int p = threadIdx.x;
    const int b = blockIdx.x;

    __shared__ float4 P[2][256];

    P[0][p] = (p == b) ? make_float4(1.0f, 0.0f, 0.0f, 0.0f)
                       : make_float4(0.0f, 0.0f, 0.0f, 0.0f);
    P[1][p] = (p == b) ? make_float4(0.0f, 0.0f, 1.0f, 0.0f)
                       : make_float4(0.0f, 0.0f, 0.0f, 0.0f);

#pragma unroll 1
    for (int i = 0; i < 256; ++i) {
        const int e0 = (2 * i) * 256 + p, e1 = e0 + 256;
        const float pe0 = pe[e0], le0 = le[e0], ie0 = ie[e0];
        const float pe1 = pe[e1], le1 = le[e1], ie1 = ie[e1];
        float po0 = 0.0f, lo0 = 0.0f, io0 = 0.0f;
        float po1 = 0.0f, lo1 = 0.0f, io1 = 0.0f;
        if (p < 255) {
            const int o0 = (2 * i) * 255 + p, o1 = o0 + 255;
            po0 = po[o0]; lo0 = lo[o0]; io0 = io[o0];
            po1 = po[o1]; lo1 = lo[o1]; io1 = io[o1];
        }

        float4 v0 = P[0][p];
        float4 v1 = P[1][p];
#pragma unroll
        for (int j = 0; j < 2; ++j) {
            float s, c;
            __sincosf(clamp02pi(j ? pe1 : pe0), &s, &c);
            const float a  = sqrtf(1.0f - (j ? le1 : le0));
            const float tt = a * sqrtf(0.5f + (j ? ie1 : ie0));
            const float rr = a * sqrtf(0.5f - (j ? ie1 : ie0));
            {
                const float ptr_ = c * v0.x - s * v0.y;
                const float pti_ = c * v0.y + s * v0.x;
                v0 = make_float4(tt * ptr_ - rr * v0.w, tt * pti_ + rr * v0.z,
                                 tt * v0.z - rr * pti_, tt * v0.w + rr * ptr_);
            }
            {
                const float ptr_ = c * v1.x - s * v1.y;
                const float pti_ = c * v1.y + s * v1.x;
                v1 = make_float4(tt * ptr_ - rr * v1.w, tt * pti_ + rr * v1.z,
                                 tt * v1.z - rr * pti_, tt * v1.w + rr * ptr_);
            }
        }
        P[0][p] = v0;
        P[1][p] = v1;
        __syncthreads();

        if (p < 255) {
            float2 top0 = make_float2(P[0][p].z, P[0][p].w);
            float2 bot0 = make_float2(P[0][p + 1].x, P[0][p + 1].y);
            float2 top1 = make_float2(P[1][p].z, P[1][p].w);
            float2 bot1 = make_float2(P[1][p + 1].x, P[1][p + 1].y);
#pragma unroll
            for (int j = 0; j < 2; ++j) {
                float s, c;
                __sincosf(clamp02pi(j ? po1 : po0), &s, &c);
                const float a  = sqrtf(1.0f - (j ? lo1 : lo0));
                const float tt = a * sqrtf(0.5f + (j ? io1 : io0));
                const float rr = a * sqrtf(0.5f - (j ? io1 : io0));
                {
                    const float ptr_ = c * top0.x - s * top0.y;
                    const float pti_ = c * top0.y + s * top0.x;
                    const float nbx = tt * bot0.x - rr * pti_;
                    const float nby = tt * bot0.y + rr * ptr_;
                    top0 = make_float2(tt * ptr_ - rr * bot0.y, tt * pti_ + rr * bot0.x);
                    bot0 = make_float2(nbx, nby);
                }
                {
                    const float ptr_ = c * top1.x - s * top1.y;
                    const float pti_ = c * top1.y + s * top1.x;
                    const float nbx = tt * bot1.x - rr * pti_;
                    const float nby = tt * bot1.y + rr * ptr_;
                    top1 = make_float2(tt * ptr_ - rr * bot1.y, tt * pti_ + rr * bot1.x);
                    bot1 = make_float2(nbx, nby);
                }
            }
            P[0][p].z = top0.x; P[0][p].w = top0.y;
            P[0][p + 1].x = bot0.x; P[0][p + 1].y = bot0.y;
            P[1][p].z = top1.x; P[1][p].w = top1.y;
            P[1][p + 1].x = bot1.x; P[1][p + 1].y = bot1.y;
        }
        __syncthreads();
    }

    const float4 v0 = P[0][p];
    const float4 v1 = P[1][p];
    float s0, c0, s1, c1;
    __sincosf(clamp02pi(pout[2 * p]),     &s0, &c0);
    __sincosf(clamp02pi(pout[2 * p + 1]), &s1, &c1);

    float4 w0, w1;
    w0.x = c0 * v0.x - s0 * v0.y;  w0.y = c0 * v0.y + s0 * v0.x;
    w0.z = c0 * v1.x - s0 * v1.y;  w0.w = c0 * v1.y + s0 * v1.x;
    w1.x = c1 * v0.z - s1 * v0.w;  w1.y = c1 * v0.w + s1 * v0.z;
    w1.z = c1 * v1.z - s1 * v1.w;  w1.w = c1 * v1.w + s1 * v1.z;

    const int i0 = (2 * p) * 512 + 2 * b;
    const int i1 = (2 * p + 1) * 512 + 2 * b;
    if (i0 + 1 < out_size) *(float2*)(out + i0) = make_float2(w0.x, w0.z);
    if (i1 + 1 < out_size) *(float2*)(out + i1) = make_float2(w1.x, w1.z);
}

extern "C" void kernel_launch(void* const* d_in, const int* in_sizes, int n_in,
                              void* d_out, int out_size, void* d_ws, size_t ws_size,
                              hipStream_t stream)
{
    const float* pe   = (const float*)d_in[0];  // pc_even_phases  [512][256]
    const float* po   = (const float*)d_in[1];  // pc_odd_phases   [512][255]
    const float* pout = (const float*)d_in[2];  // pc_out_phases   [512]
    const float* le   = (const float*)d_in[3];  // mmi_loss_even   [512][256]
    const float* ie   = (const float*)d_in[4];  // mmi_imb_even    [512][256]
    const float* lo   = (const float*)d_in[5];  // mmi_loss_odd    [512][255]
    const float* io   = (const float*)d_in[6];  // mmi_imb_odd     [512][255]

    const size_t need = (size_t)128 * 1024 * sizeof(uint4);  // 2 MB
    if (ws_size >= need) {
        uint4* Mch8 = (uint4*)d_ws;
        compose8q_kernel<<<512, 320, 0, stream>>>(pe, po, le, ie, lo, io, Mch8);
        mesh8p_kernel<<<512, 256, 0, stream>>>(Mch8, pout, (float*)d_out, out_size);
    } else {
        mesh_kernel<<<256, 256, 0, stream>>>(pe, po, pout, le, ie, lo, io,
                                             (float*)d_out, out_size);
    }
}

// Round 14
// 127.266 us; speedup vs baseline: 1.0681x; 1.0681x over previous
//
#include <hip/hip_runtime.h>
#include <hip/hip_fp16.h>

#define TWO_PI_F 6.283185307179586f

__device__ __forceinline__ float clamp02pi(float x) {
    return fminf(fmaxf(x, 0.0f), TWO_PI_F);
}

__device__ __forceinline__ float2 cmul(const float2 a, const float2 b) {
    return make_float2(a.x * b.x - a.y * b.y, a.x * b.y + a.y * b.x);
}
__device__ __forceinline__ float2 cadd(const float2 a, const float2 b) {
    return make_float2(a.x + b.x, a.y + b.y);
}
__device__ __forceinline__ float2 cscale(const float s, const float2 a) {
    return make_float2(s * a.x, s * a.y);
}
__device__ __forceinline__ float2 imul(const float r, const float2 e) {  // i*r*e
    return make_float2(-r * e.y, r * e.x);
}
__device__ __forceinline__ float2 cfma(const float2 acc, const float2 a, const float2 b) {
    return make_float2(acc.x + a.x * b.x - a.y * b.y,
                       acc.y + a.x * b.y + a.y * b.x);
}

// half2 <-> float2 via bit_cast (register-only).
__device__ __forceinline__ float2 h2f(const unsigned u) {
    return __half22float2(__builtin_bit_cast(__half2, u));
}
__device__ __forceinline__ unsigned f2h(const float2 f) {
    return __builtin_bit_cast(unsigned, __float22half2_rn(f));
}

// Band-4 composition of row r for one 4-layer step, WINDOWED pair coefs
// (math verbatim R12-R18 — verified, absmax 7.45e-9 on the fp16 path).
__device__ __forceinline__ void compose_row_w(
    const float4 (*sE)[72], const float4 (*sO)[72], const int r, const int P0,
    float4& h0, float4& h1)
{
    float2 f0, f1, f2, f3;
    if (r == 0) {
        const float4 q1 = sE[1][0], q0 = sE[0][0];   // P0 == 0 for quarter 0
        const float2 e1 = make_float2(q1.x, q1.y);
        const float2 e0 = make_float2(q0.x, q0.y);
        const float2 v2 = cscale(q1.z, e1);
        const float2 v3 = make_float2(0.0f, q1.w);
        f2 = cadd(cmul(v2, cscale(q0.z, e0)), cmul(v3, imul(q0.w, e0)));
        f3 = cadd(cmul(v2, make_float2(0.0f, q0.w)), cscale(q0.z, v3));
        f0 = make_float2(0.0f, 0.0f);
        f1 = make_float2(0.0f, 0.0f);
    } else {
        const int pidx = ((r - 1) >> 1) - P0;
        const int qidx = min(((r - 1) >> 1) + 1, 255) - P0;
        const float4 qO1 = sO[1][pidx], qO0 = sO[0][pidx];
        const float2 eO1 = make_float2(qO1.x, qO1.y);
        const float2 eO0 = make_float2(qO0.x, qO0.y);
        float2 w1, w2;
        if (r & 1) { w1 = cscale(qO1.z, eO1); w2 = make_float2(0.0f, qO1.w); }
        else       { w1 = imul(qO1.w, eO1);   w2 = make_float2(qO1.z, 0.0f); }
        const float2 u1 = cadd(cmul(w1, cscale(qO0.z, eO0)),
                               cmul(w2, imul(qO0.w, eO0)));
        const float2 u2 = cadd(cmul(w1, make_float2(0.0f, qO0.w)),
                               cscale(qO0.z, w2));
        const float4 qE1p = sE[1][pidx], qE1q = sE[1][qidx];
        const float4 qE0p = sE[0][pidx], qE0q = sE[0][qidx];
        const float2 eE1p = make_float2(qE1p.x, qE1p.y);
        const float2 eE1q = make_float2(qE1q.x, qE1q.y);
        const float2 eE0p = make_float2(qE0p.x, qE0p.y);
        const float2 eE0q = make_float2(qE0q.x, qE0q.y);
        const float2 v0 = cmul(u1, imul(qE1p.w, eE1p));
        const float2 v1 = cscale(qE1p.z, u1);
        const float2 v2 = cmul(u2, cscale(qE1q.z, eE1q));
        const float2 v3 = cmul(u2, make_float2(0.0f, qE1q.w));
        f0 = cadd(cmul(v0, cscale(qE0p.z, eE0p)), cmul(v1, imul(qE0p.w, eE0p)));
        f1 = cadd(cmul(v0, make_float2(0.0f, qE0p.w)), cscale(qE0p.z, v1));
        f2 = cadd(cmul(v2, cscale(qE0q.z, eE0q)), cmul(v3, imul(qE0q.w, eE0q)));
        f3 = cadd(cmul(v2, make_float2(0.0f, qE0q.w)), cscale(qE0q.z, v3));
    }
    h0 = make_float4(f0.x, f0.y, f1.x, f1.y);
    h1 = make_float4(f2.x, f2.y, f3.x, f3.y);
}

// ---------------------------------------------------------------------------
// Kernel 1: quarter-superstep composition — R8 rebalanced version (verified).
// Row-direct output layout:
//   Mch8[j*1024 + r] = band cols 0..3 ; Mch8[j*1024 + 512 + r] = cols 4..7
// ---------------------------------------------------------------------------
__global__ __launch_bounds__(320) void compose8q_kernel(
    const float* __restrict__ pe, const float* __restrict__ po,
    const float* __restrict__ le, const float* __restrict__ ie,
    const float* __restrict__ lo, const float* __restrict__ io,
    uint4* __restrict__ Mch8)
{
    const int q = blockIdx.x;
    const int j = q >> 2;
    const int quarter = q & 3;
    const int R0 = 128 * quarter;
    const int P0 = (quarter == 0) ? 0 : ((R0 - 3) >> 1);
    const int t = threadIdx.x;

    __shared__ float4 sE[4][72];
    __shared__ float4 sO[4][72];
    __shared__ float4 B4[2][134][2];

    // ---- Phase A: stage pair-coef window [P0, P0+72) (2 passes @320) ----
    for (int it = t; it < 576; it += 320) {
        const int half = it / 288;
        const int rem  = it % 288;
        const int sub  = rem / 72;
        const int w    = rem % 72;
        const int p    = P0 + w;
        if (p > 255) continue;
        if (half == 0) {
            const int idx = (4 * j + sub) * 256 + p;
            float s, c;
            __sincosf(clamp02pi(pe[idx]), &s, &c);
            const float a = sqrtf(1.0f - le[idx]);
            sE[sub][w] = make_float4(c, s, a * sqrtf(0.5f + ie[idx]),
                                           a * sqrtf(0.5f - ie[idx]));
        } else {
            float4 qv = make_float4(1.0f, 0.0f, 1.0f, 0.0f);
            if (p < 255) {
                const int odx = (4 * j + sub) * 255 + p;
                float s, c;
                __sincosf(clamp02pi(po[odx]), &s, &c);
                const float a = sqrtf(1.0f - lo[odx]);
                qv = make_float4(c, s, a * sqrtf(0.5f + io[odx]),
                                       a * sqrtf(0.5f - io[odx]));
            }
            sO[sub][w] = qv;
        }
    }
    __syncthreads();

    // ---- Phase B: band-4 for both child steps, rows [R0-2, R0+131] ----
    if (t < 268) {
        const int s = t / 134, slot = t % 134;
        const int row = R0 - 2 + slot;
        if (row >= 0 && row <= 511) {
            float4 h0, h1;
            compose_row_w(&sE[2 * s], &sO[2 * s], row, P0, h0, h1);
            B4[s][slot][0] = h0;
            B4[s][slot][1] = h1;
        }
    }
    __syncthreads();

    // ---- Phase C: band-8 product, rows R0..R0+127, 2 threads/row ----
    if (t < 256) {
        const int rr_  = t & 127;
        const int half = t >> 7;
        const int r = R0 + rr_;
        const int base = (r & 1) ? (r - 1) : (r - 2);
        const int sr = rr_ + 2;
        const float4 wv0 = B4[1][sr][0], wv1 = B4[1][sr][1];
        const float2 w0 = make_float2(wv0.x, wv0.y), w1 = make_float2(wv0.z, wv0.w);
        const float2 w2 = make_float2(wv1.x, wv1.y), w3 = make_float2(wv1.z, wv1.w);
        uint4* dst = Mch8 + (size_t)j * 1024 + r;     // row-direct layout

        if (half == 0) {
            float2 p0 = make_float2(0.f,0.f), p1 = p0, p2 = p0, p3 = p0;
            {   const int k = min(max(base, 0), 511) - (R0 - 2);
                const float4 a = B4[0][k][0], b = B4[0][k][1];
                p0 = cfma(p0, w0, make_float2(a.x, a.y));
                p1 = cfma(p1, w0, make_float2(a.z, a.w));
                p2 = cfma(p2, w0, make_float2(b.x, b.y));
                p3 = cfma(p3, w0, make_float2(b.z, b.w)); }
            {   const int k = min(max(base + 1, 0), 511) - (R0 - 2);
                const float4 a = B4[0][k][0];
                p2 = cfma(p2, w1, make_float2(a.x, a.y));
                p3 = cfma(p3, w1, make_float2(a.z, a.w)); }
            {   const int k = min(max(base + 2, 0), 511) - (R0 - 2);
                const float4 a = B4[0][k][0];
                p2 = cfma(p2, w2, make_float2(a.x, a.y));
                p3 = cfma(p3, w2, make_float2(a.z, a.w)); }
            dst[0] = make_uint4(f2h(p0), f2h(p1), f2h(p2), f2h(p3));
        } else {
            float2 p4 = make_float2(0.f,0.f), p5 = p4, p6 = p4, p7 = p4;
            {   const int k = min(max(base + 1, 0), 511) - (R0 - 2);
                const float4 b = B4[0][k][1];
                p4 = cfma(p4, w1, make_float2(b.x, b.y));
                p5 = cfma(p5, w1, make_float2(b.z, b.w)); }
            {   const int k = min(max(base + 2, 0), 511) - (R0 - 2);
                const float4 b = B4[0][k][1];
                p4 = cfma(p4, w2, make_float2(b.x, b.y));
                p5 = cfma(p5, w2, make_float2(b.z, b.w)); }
            {   const int k = min(max(base + 3, 0), 511) - (R0 - 2);
                const float4 a = B4[0][k][0], b = B4[0][k][1];
                p4 = cfma(p4, w3, make_float2(a.x, a.y));
                p5 = cfma(p5, w3, make_float2(a.z, a.w));
                p6 = cfma(p6, w3, make_float2(b.x, b.y));
                p7 = cfma(p7, w3, make_float2(b.z, b.w)); }
            dst[512] = make_uint4(f2h(p4), f2h(p5), f2h(p6), f2h(p7));
        }
    }
}

// Complex FMA with fp16-packed coefficient, f32 accumulate, via v_fma_mix
// (exact f16->f32 convert folded into the f32 fma; R4/R5 measured
// bit-identical absmax vs the h2f-then-cfma path).
__device__ __forceinline__ float2 chmix(float2 acc, const unsigned h,
                                        const float2 b)
{
    const __half2 k = __builtin_bit_cast(__half2, h);
    const float kx = __low2float(k);
    const float ky = __high2float(k);
    acc.x = fmaf(kx,  b.x, acc.x);
    acc.x = fmaf(-ky, b.y, acc.x);
    acc.y = fmaf(kx,  b.y, acc.y);
    acc.y = fmaf(ky,  b.x, acc.y);
    return acc;
}

// Band-8 row apply: coefs ca (slots w0,w1) then cb (slots w2,w3), ascending —
// exact order of the verified path (R4/R5-verified numerics).
__device__ __forceinline__ float2 row8m(const uint4 ca, const uint4 cb,
    const float4 w0, const float4 w1, const float4 w2, const float4 w3)
{
    float2 a = make_float2(0.f, 0.f);
    a = chmix(a, ca.x, make_float2(w0.x, w0.y));
    a = chmix(a, ca.y, make_float2(w0.z, w0.w));
    a = chmix(a, ca.z, make_float2(w1.x, w1.y));
    a = chmix(a, ca.w, make_float2(w1.z, w1.w));
    a = chmix(a, cb.x, make_float2(w2.x, w2.y));
    a = chmix(a, cb.y, make_float2(w2.z, w2.w));
    a = chmix(a, cb.z, make_float2(w3.x, w3.y));
    a = chmix(a, cb.w, make_float2(w3.z, w3.w));
    return a;
}

// ---------------------------------------------------------------------------
// Kernel 2: PAIR-per-thread band-8 scan — R12 FINAL configuration (verbatim;
// best measured: mesh 62.1 us, total 127.3 us, absmax 7.450581e-9).
// R13's unroll-x2 regressed (VGPR 44->60, 69.5 us) -> reverted per
// pre-commit. Levers in this config, each A/B-measured:
//  - counted barrier (drain DS only; coef prefetch in flight across it): -10%
//  - narrow s_setprio(1) around the FMA cluster only (T5; wide region
//    regressed): -8%
//  - own-pair q2 from registers + critical-path ds_reads first: -6%
//    (neutral pre-setprio, pays once blocks antiphase)
// VALU ~51% + LDS-pipe ~41%, co-binding and overlapped; all structural
// alternatives measured worse (occupancy sweep 2-16 waves/CU, shuffle halos,
// coalesced transpose, dual-column, compose rebalance).
// ---------------------------------------------------------------------------
__global__ __launch_bounds__(256) void mesh8p_kernel(
    const uint4* __restrict__ Mch,
    const float* __restrict__ pout,
    float* __restrict__ out, const int out_size)
{
    const int t   = threadIdx.x;   // pair 0..255
    const int col = blockIdx.x;    // column 0..511
    const int r0  = 2 * t, r1 = r0 + 1;

    __shared__ float4 S[2][264];   // [buf][pair+2] = {T.x,T.y,B.x,B.y}

    float2 Y0 = make_float2((r0 == col) ? 1.0f : 0.0f, 0.0f);
    float2 Y1 = make_float2((r1 == col) ? 1.0f : 0.0f, 0.0f);
    S[0][t + 2] = make_float4(Y0.x, Y0.y, Y1.x, Y1.y);
    if (t < 2) {
        const float4 z = make_float4(0.f, 0.f, 0.f, 0.f);
        S[0][t] = z; S[1][t] = z;
        S[0][258 + t] = z; S[1][258 + t] = z;
    }

    uint4 c0e = Mch[r0], c1e = Mch[512 + r0];   // coefs rows 2t, 2t+1
    uint4 c0o = Mch[r1], c1o = Mch[512 + r1];
    __syncthreads();

#pragma unroll 1
    for (int i = 0; i < 128; ++i) {
        // critical-path LDS reads first; own pair from registers
        const float4* SS = S[i & 1];
        const float4 q0 = SS[t],     q1 = SS[t + 1],
                     q3 = SS[t + 3], q4 = SS[t + 4];
        const float4 q2 = make_float4(Y0.x, Y0.y, Y1.x, Y1.y);

        const int nb = ((i + 1) & 127) * 1024;          // prefetch (wrap ok)
        const uint4 n0e = Mch[nb + r0], n1e = Mch[nb + 512 + r0];
        const uint4 n0o = Mch[nb + r1], n1o = Mch[nb + 512 + r1];

        // even row 2t: slots t..t+3; odd row 2t+1: slots t+1..t+4
        // (identical fma order to the verified path). T5 narrow: raise
        // priority through the FMA cluster only (R10 measured best).
        __builtin_amdgcn_s_setprio(1);
        Y0 = row8m(c0e, c1e, q0, q1, q2, q3);
        Y1 = row8m(c0o, c1o, q1, q2, q3, q4);
        __builtin_amdgcn_s_setprio(0);

        S[(i + 1) & 1][t + 2] = make_float4(Y0.x, Y0.y, Y1.x, Y1.y);

        // Counted barrier: drain DS only; global prefetch stays in flight.
        __builtin_amdgcn_sched_barrier(0);
        asm volatile("s_waitcnt lgkmcnt(0)" ::: "memory");
        __builtin_amdgcn_s_barrier();
        __builtin_amdgcn_sched_barrier(0);

        c0e = n0e; c1e = n1e; c0o = n0o; c1o = n1o;
    }

    // ---- output phase; expected output = Re(M), row-major, guarded ----
    float s0, cc0, s1, cc1;
    __sincosf(clamp02pi(pout[r0]), &s0, &cc0);
    __sincosf(clamp02pi(pout[r1]), &s1, &cc1);
    const int o0 = r0 * 512 + col;
    const int o1 = r1 * 512 + col;
    if (o0 < out_size) out[o0] = cc0 * Y0.x - s0 * Y0.y;
    if (o1 < out_size) out[o1] = cc1 * Y1.x - s1 * Y1.y;
}

// ---------------------------------------------------------------------------
// Fallback (verbatim R5 kernel, known-passing) — used only if ws too small.
// ---------------------------------------------------------------------------
__global__ __launch_bounds__(256) void mesh_kernel(
    const float* __restrict__ pe, const float* __restrict__ po,
    const float* __restrict__ pout,
    const float* __restrict__ le, const float* __restrict__ ie,
    const float* __restrict__ lo, const float* __restrict__ io,
    float* __restrict__ out, const int out_size)
{
    const int p = threadIdx.x;
    const int b = blockIdx.x;

    __shared__ float4 P[2][256];

    P[0][p] = (p == b) ? make_float4(1.0f, 0.0f, 0.0f, 0.0f)
                       : make_float4(0.0f, 0.0f, 0.0f, 0.0f);
    P[1][p] = (p == b) ? make_float4(0.0f, 0.0f, 1.0f, 0.0f)
                       : make_float4(0.0f, 0.0f, 0.0f, 0.0f);

#pragma unroll 1
    for (int i = 0; i < 256; ++i) {
        const int e0 = (2 * i) * 256 + p, e1 = e0 + 256;
        const float pe0 = pe[e0], le0 = le[e0], ie0 = ie[e0];
        const float pe1 = pe[e1], le1 = le[e1], ie1 = ie[e1];
        float po0 = 0.0f, lo0 = 0.0f, io0 = 0.0f;
        float po1 = 0.0f, lo1 = 0.0f, io1 = 0.0f;
        if (p < 255) {
            const int o0 = (2 * i) * 255 + p, o1 = o0 + 255;
            po0 = po[o0]; lo0 = lo[o0]; io0 = io[o0];
            po1 = po[o1]; lo1 = lo[o1]; io1 = io[o1];
        }

        float4 v0 = P[0][p];
        float4 v1 = P[1][p];
#pragma unroll
        for (int j = 0; j < 2; ++j) {
            float s, c;
            __sincosf(clamp02pi(j ? pe1 : pe0), &s, &c);
            const float a  = sqrtf(1.0f - (j ? le1 : le0));
            const float tt = a * sqrtf(0.5f + (j ? ie1 : ie0));
            const float rr = a * sqrtf(0.5f - (j ? ie1 : ie0));
            {
                const float ptr_ = c * v0.x - s * v0.y;
                const float pti_ = c * v0.y + s * v0.x;
                v0 = make_float4(tt * ptr_ - rr * v0.w, tt * pti_ + rr * v0.z,
                                 tt * v0.z - rr * pti_, tt * v0.w + rr * ptr_);
            }
            {
                const float ptr_ = c * v1.x - s * v1.y;
                const float pti_ = c * v1.y + s * v1.x;
                v1 = make_float4(tt * ptr_ - rr * v1.w, tt * pti_ + rr * v1.z,
                                 tt * v1.z - rr * pti_, tt * v1.w + rr * ptr_);
            }
        }
        P[0][p] = v0;
        P[1][p] = v1;
        __syncthreads();

        if (p < 255) {
            float2 top0 = make_float2(P[0][p].z, P[0][p].w);
            float2 bot0 = make_float2(P[0][p + 1].x, P[0][p + 1].y);
            float2 top1 = make_float2(P[1][p].z, P[1][p].w);
            float2 bot1 = make_float2(P[1][p + 1].x, P[1][p + 1].y);
#pragma unroll
            for (int j = 0; j < 2; ++j) {
                float s, c;
                __sincosf(clamp02pi(j ? po1 : po0), &s, &c);
                const float a  = sqrtf(1.0f - (j ? lo1 : lo0));
                const float tt = a * sqrtf(0.5f + (j ? io1 : io0));
                const float rr = a * sqrtf(0.5f - (j ? io1 : io0));
                {
                    const float ptr_ = c * top0.x - s * top0.y;
                    const float pti_ = c * top0.y + s * top0.x;
                    const float nbx = tt * bot0.x - rr * pti_;
                    const float nby = tt * bot0.y + rr * ptr_;
                    top0 = make_float2(tt * ptr_ - rr * bot0.y, tt * pti_ + rr * bot0.x);
                    bot0 = make_float2(nbx, nby);
                }
                {
                    const float ptr_ = c * top1.x - s * top1.y;
                    const float pti_ = c * top1.y + s * top1.x;
                    const float nbx = tt * bot1.x - rr * pti_;
                    const float nby = tt * bot1.y + rr * ptr_;
                    top1 = make_float2(tt * ptr_ - rr * bot1.y, tt * pti_ + rr * bot1.x);
                    bot1 = make_float2(nbx, nby);
                }
            }
            P[0][p].z = top0.x; P[0][p].w = top0.y;
            P[0][p + 1].x = bot0.x; P[0][p + 1].y = bot0.y;
            P[1][p].z = top1.x; P[1][p].w = top1.y;
            P[1][p + 1].x = bot1.x; P[1][p + 1].y = bot1.y;
        }
        __syncthreads();
    }

    const float4 v0 = P[0][p];
    const float4 v1 = P[1][p];
    float s0, c0, s1, c1;
    __sincosf(clamp02pi(pout[2 * p]),     &s0, &c0);
    __sincosf(clamp02pi(pout[2 * p + 1]), &s1, &c1);

    float4 w0, w1;
    w0.x = c0 * v0.x - s0 * v0.y;  w0.y = c0 * v0.y + s0 * v0.x;
    w0.z = c0 * v1.x - s0 * v1.y;  w0.w = c0 * v1.y + s0 * v1.x;
    w1.x = c1 * v0.z - s1 * v0.w;  w1.y = c1 * v0.w + s1 * v0.z;
    w1.z = c1 * v1.z - s1 * v1.w;  w1.w = c1 * v1.w + s1 * v1.z;

    const int i0 = (2 * p) * 512 + 2 * b;
    const int i1 = (2 * p + 1) * 512 + 2 * b;
    if (i0 + 1 < out_size) *(float2*)(out + i0) = make_float2(w0.x, w0.z);
    if (i1 + 1 < out_size) *(float2*)(out + i1) = make_float2(w1.x, w1.z);
}

extern "C" void kernel_launch(void* const* d_in, const int* in_sizes, int n_in,
                              void* d_out, int out_size, void* d_ws, size_t ws_size,
                              hipStream_t stream)
{
    const float* pe   = (const float*)d_in[0];  // pc_even_phases  [512][256]
    const float* po   = (const float*)d_in[1];  // pc_odd_phases   [512][255]
    const float* pout = (const float*)d_in[2];  // pc_out_phases   [512]
    const float* le   = (const float*)d_in[3];  // mmi_loss_even   [512][256]
    const float* ie   = (const float*)d_in[4];  // mmi_imb_even    [512][256]
    const float* lo   = (const float*)d_in[5];  // mmi_loss_odd    [512][255]
    const float* io   = (const float*)d_in[6];  // mmi_imb_odd     [512][255]

    const size_t need = (size_t)128 * 1024 * sizeof(uint4);  // 2 MB
    if (ws_size >= need) {
        uint4* Mch8 = (uint4*)d_ws;
        compose8q_kernel<<<512, 320, 0, stream>>>(pe, po, le, ie, lo, io, Mch8);
        mesh8p_kernel<<<512, 256, 0, stream>>>(Mch8, pout, (float*)d_out, out_size);
    } else {
        mesh_kernel<<<256, 256, 0, stream>>>(pe, po, pout, le, ie, lo, io,
                                             (float*)d_out, out_size);
    }
}